// Round 2
// baseline (2616.056 us; speedup 1.0000x reference)
//
#include <hip/hip_runtime.h>
#include <cmath>

#ifndef M_PI
#define M_PI 3.14159265358979323846
#endif

// Problem constants
#define NH 32      // H
#define NW 32      // W
#define NP 64      // P (state channels)
#define NU 64      // U (io channels)
#define NL 32      // L
#define NB 8       // batch
#define NIMG 256       // L*B
#define NIMG_TOT 264   // + B images for x0
#define HWN 1024       // H*W
#define IMG_STRIDE 65536  // HWN*NP (elements; float2 for complex buffers)

// ---------------------------------------------------------------------------
// K0: S matrix (32x32 DST-I, real symmetric involutive) + kv from softmax(values)
// ---------------------------------------------------------------------------
__global__ void k_setup(const float* __restrict__ values, float* __restrict__ S,
                        float* __restrict__ kv) {
  int t = threadIdx.x;
  int i = t >> 5, j = t & 31;
  double s = sin(M_PI * (double)((i + 1) * (j + 1)) / 33.0) / sqrt(16.5);
  S[t] = (float)s;
  if (t < NP) {
    float v0 = values[t * 4 + 0], v1 = values[t * 4 + 1];
    float v2 = values[t * 4 + 2], v3 = values[t * 4 + 3];
    float m = fmaxf(fmaxf(v0, v1), fmaxf(v2, v3));
    float e0 = expf(v0 - m), e1 = expf(v1 - m), e2 = expf(v2 - m), e3 = expf(v3 - m);
    float inv = 4.0f / (e0 + e1 + e2 + e3);
    float xk = e0 * inv, yk = e1 * inv, zk = e2 * inv, wk = e3 * inv;
    kv[t * 4 + 0] = (xk + yk - 2.0f) * 0.25f;
    kv[t * 4 + 1] = (xk + zk - 2.0f) * 0.25f;
    kv[t * 4 + 2] = (xk + wk - 2.0f) * 0.125f;
    kv[t * 4 + 3] = 0.f;
  }
}

// ---------------------------------------------------------------------------
// K1: A_bar[n][p], B_coeff[n][p] (n = h*32+w spectral index), double precision
// ---------------------------------------------------------------------------
__global__ void k_coeff(const float* __restrict__ Lre, const float* __restrict__ Lim,
                        const float* __restrict__ log_step, const float* __restrict__ kv,
                        float2* __restrict__ A, float2* __restrict__ Bc) {
  int tid = blockIdx.x * blockDim.x + threadIdx.x;  // 65536 threads
  int n = tid >> 6, p = tid & 63;
  int h = n >> 5, w = n & 31;
  double ch = 2.0 * cos(M_PI * (double)(h + 1) / 33.0);
  double cw = 2.0 * cos(M_PI * (double)(w + 1) / 33.0);
  double Dv = (double)kv[p * 4 + 0] * cw + (double)kv[p * 4 + 1] * ch +
              (double)kv[p * 4 + 2] * ch * cw + 1.0;
  double lr = fmin((double)Lre[p], -0.0001);
  double li = (double)Lim[p];
  double tr = lr * Dv, ti = li * Dv;                 // temp = Lambda * D
  double st = exp((double)log_step[p]);
  double zr = tr * st, zi = ti * st;
  double ea = exp(zr);
  double Ar = ea * cos(zi), Ai = ea * sin(zi);       // A_bar = exp(temp*step)
  double d = tr * tr + ti * ti;                      // B_coeff = (A-1)/temp
  double br = ((Ar - 1.0) * tr + Ai * ti) / d;
  double bi = (Ai * tr - (Ar - 1.0) * ti) / d;
  A[tid]  = make_float2((float)Ar, (float)Ai);
  Bc[tid] = make_float2((float)br, (float)bi);
}

// ---------------------------------------------------------------------------
// K2: fused conv with B_r + i*B_i over 264 images (u then x0), SAME 3x3,
//     output Bu' = (-i)^(h+w+2) * Bu   (forward DST phase pre-applied)
//     layout XBUF[img][h][w][p] float2
// ---------------------------------------------------------------------------
__global__ __launch_bounds__(256) void k_convB(const float* __restrict__ u,
                                               const float* __restrict__ x0,
                                               const float* __restrict__ Br,
                                               const float* __restrict__ Bi,
                                               float2* __restrict__ XBUF) {
  int img = blockIdx.x, h = blockIdx.y;
  __shared__ float tin[3][34][64];  // rows h-1..h+1, w padded by 1 each side
  const float* src = (img < NIMG) ? (u + (size_t)img * HWN * NU)
                                  : (x0 + (size_t)(img - NIMG) * HWN * NU);
  int t = threadIdx.x;
  for (int idx = t; idx < 3 * 34 * 64; idx += 256) {
    int c = idx & 63; int rem = idx >> 6; int wc = rem % 34; int r = rem / 34;
    int hh = h - 1 + r, wg = wc - 1;
    float v = 0.f;
    if (hh >= 0 && hh < NH && wg >= 0 && wg < NW) v = src[(size_t)(hh * NW + wg) * NU + c];
    tin[r][wc][c] = v;
  }
  __syncthreads();
  int p = t & 63, wq = t >> 6;   // p = out channel; thread owns w = wq*8 + k
  float2 acc[8];
#pragma unroll
  for (int k = 0; k < 8; k++) acc[k] = make_float2(0.f, 0.f);
  for (int kh = 0; kh < 3; kh++)
    for (int kw = 0; kw < 3; kw++) {
      const float* br = Br + (size_t)((kh * 3 + kw) * 64) * 64 + p;
      const float* bi = Bi + (size_t)((kh * 3 + kw) * 64) * 64 + p;
#pragma unroll 4
      for (int c = 0; c < 64; c++) {
        float wr = br[(size_t)c * 64];
        float wi = bi[(size_t)c * 64];
#pragma unroll
        for (int k = 0; k < 8; k++) {
          float x = tin[kh][wq * 8 + k + kw][c];   // broadcast across wave
          acc[k].x = fmaf(x, wr, acc[k].x);
          acc[k].y = fmaf(x, wi, acc[k].y);
        }
      }
    }
  size_t base = (size_t)img * IMG_STRIDE + (size_t)h * NW * NP;
#pragma unroll
  for (int k = 0; k < 8; k++) {
    int w = wq * 8 + k;
    int m = (h + w + 2) & 3;   // multiply by (-i)^m
    float r = acc[k].x, im = acc[k].y;
    float2 o;
    if (m == 0)      o = make_float2( r,  im);
    else if (m == 1) o = make_float2( im, -r);
    else if (m == 2) o = make_float2(-r, -im);
    else             o = make_float2(-im,  r);
    XBUF[base + (size_t)w * NP + p] = o;
  }
}

// ---------------------------------------------------------------------------
// K3: forward DST IN-PLACE: XBUF[img][a][c][p] = Bc[a,c,p]*(S·XBUF·S^T)[a,c,p]
//     Safe in-place: each block loads its whole (img, 4-p) slice to LDS before
//     any global write; blocks touch disjoint slices.
// ---------------------------------------------------------------------------
__global__ __launch_bounds__(256) void k_dst_fwd(float2* __restrict__ XBUF,
                                                 const float* __restrict__ S,
                                                 const float2* __restrict__ Bc) {
  int img = blockIdx.x;
  int p0 = blockIdx.y * 4;
  __shared__ float2 tin[32][32][4];  // [h][w][pp]
  __shared__ float2 t1[32][32][4];   // [a][w][pp]
  int t = threadIdx.x;
  float2* base = XBUF + (size_t)img * IMG_STRIDE;
  for (int idx = t; idx < 4096; idx += 256) {
    int pp = idx & 3, w = (idx >> 2) & 31, hh = idx >> 7;
    tin[hh][w][pp] = base[(size_t)(hh * 32 + w) * 64 + p0 + pp];
  }
  __syncthreads();
  {  // stage 1: t1[a][w] = sum_h S[a,h] * tin[h][w]
    int pp = t & 3, w = (t >> 2) & 31, a0 = t >> 7;
    for (int k = 0; k < 16; k++) {
      int a = a0 * 16 + k;
      float2 s = make_float2(0.f, 0.f);
#pragma unroll 8
      for (int hh = 0; hh < 32; hh++) {
        float sv = S[a * 32 + hh];
        float2 v = tin[hh][w][pp];
        s.x = fmaf(sv, v.x, s.x);
        s.y = fmaf(sv, v.y, s.y);
      }
      t1[a][w][pp] = s;
    }
  }
  __syncthreads();
  {  // stage 2: out[a][c] = sum_w t1[a][w] * S[c,w]; multiply B_coeff; store
    int pp = t & 3, c = (t >> 2) & 31, a0 = t >> 7;
    for (int k = 0; k < 16; k++) {
      int a = a0 * 16 + k;
      float2 s = make_float2(0.f, 0.f);
#pragma unroll 8
      for (int w = 0; w < 32; w++) {
        float sv = S[c * 32 + w];
        float2 v = t1[a][w][pp];
        s.x = fmaf(sv, v.x, s.x);
        s.y = fmaf(sv, v.y, s.y);
      }
      int n = a * 32 + c;
      float2 bc = Bc[(size_t)n * 64 + p0 + pp];
      float2 o = make_float2(s.x * bc.x - s.y * bc.y, s.x * bc.y + s.y * bc.x);
      base[(size_t)n * 64 + p0 + pp] = o;
    }
  }
}

// ---------------------------------------------------------------------------
// K4: in-place scan over l. x_{-1} = x0_hat (imgs 256..263). X[l*8+b] updated.
// ---------------------------------------------------------------------------
__global__ __launch_bounds__(256) void k_scan(const float2* __restrict__ A,
                                              float2* __restrict__ X) {
  int gx = blockIdx.x;            // 2048 blocks
  int b = gx >> 8, a = (gx >> 3) & 31, cg = gx & 7;
  int t = threadIdx.x;
  int c = cg * 4 + (t >> 6), p = t & 63;
  size_t off = (size_t)(a * 32 + c) * 64 + p;
  float2 Av = A[off];
  float2 x = X[(size_t)(NIMG + b) * IMG_STRIDE + off];   // x0_hat
  for (int l = 0; l < NL; l++) {
    size_t idx = (size_t)(l * NB + b) * IMG_STRIDE + off;
    float2 v = X[idx];
    float2 nx;
    nx.x = Av.x * x.x - Av.y * x.y + v.x;
    nx.y = Av.x * x.y + Av.y * x.x + v.y;
    x = nx;
    X[idx] = x;
  }
}

// ---------------------------------------------------------------------------
// K5: inverse DST IN-PLACE (imgs 0..255):
//     XBUF[img][h][w][p] = i^(h+w+2) * (S · XBUF · S^T)[h,w,p]
// ---------------------------------------------------------------------------
__global__ __launch_bounds__(256) void k_dst_inv(float2* __restrict__ XBUF,
                                                 const float* __restrict__ S) {
  int img = blockIdx.x;
  int p0 = blockIdx.y * 4;
  __shared__ float2 xin[32][32][4];  // [a][c][pp]
  __shared__ float2 t1[32][32][4];   // [h][c][pp]
  int t = threadIdx.x;
  float2* base = XBUF + (size_t)img * IMG_STRIDE;
  for (int idx = t; idx < 4096; idx += 256) {
    int pp = idx & 3, c = (idx >> 2) & 31, a = idx >> 7;
    xin[a][c][pp] = base[(size_t)(a * 32 + c) * 64 + p0 + pp];
  }
  __syncthreads();
  {  // stage 1: t1[h][c] = sum_a S[h,a] * xin[a][c]
    int pp = t & 3, c = (t >> 2) & 31, h0 = t >> 7;
    for (int k = 0; k < 16; k++) {
      int h = h0 * 16 + k;
      float2 s = make_float2(0.f, 0.f);
#pragma unroll 8
      for (int a = 0; a < 32; a++) {
        float sv = S[h * 32 + a];
        float2 v = xin[a][c][pp];
        s.x = fmaf(sv, v.x, s.x);
        s.y = fmaf(sv, v.y, s.y);
      }
      t1[h][c][pp] = s;
    }
  }
  __syncthreads();
  {  // stage 2: out[h][w] = sum_c S[w,c] * t1[h][c]; apply i^(h+w+2); store
    int pp = t & 3, w = (t >> 2) & 31, h0 = t >> 7;
    for (int k = 0; k < 16; k++) {
      int h = h0 * 16 + k;
      float2 s = make_float2(0.f, 0.f);
#pragma unroll 8
      for (int c = 0; c < 32; c++) {
        float sv = S[w * 32 + c];
        float2 v = t1[h][c][pp];
        s.x = fmaf(sv, v.x, s.x);
        s.y = fmaf(sv, v.y, s.y);
      }
      int m = (h + w + 2) & 3;  // multiply by i^m
      float2 o;
      if (m == 0)      o = make_float2( s.x,  s.y);
      else if (m == 1) o = make_float2(-s.y,  s.x);
      else if (m == 2) o = make_float2(-s.x, -s.y);
      else             o = make_float2( s.y, -s.x);
      base[(size_t)(h * 32 + w) * 64 + p0 + pp] = o;
    }
  }
}

// ---------------------------------------------------------------------------
// K6: y = gelu( 2*(conv(xr,C_r) - conv(xi,C_i)) + conv(u,D) )
//     block = (img, h, half-row); single accumulator with folded 2x / -2x.
// ---------------------------------------------------------------------------
__global__ __launch_bounds__(256) void k_convCD(const float2* __restrict__ XSP,
                                                const float* __restrict__ u,
                                                const float* __restrict__ Cr,
                                                const float* __restrict__ Ci,
                                                const float* __restrict__ Dk,
                                                float* __restrict__ out) {
  int img = blockIdx.x, h = blockIdx.y, half = blockIdx.z;
  __shared__ float2 xin[3][18][64];
  __shared__ float uin[3][18][64];
  int t = threadIdx.x;
  int wbase = half * 16;
  const float2* xsrc = XSP + (size_t)img * IMG_STRIDE;
  const float* usrc = u + (size_t)img * HWN * NU;
  for (int idx = t; idx < 3 * 18 * 64; idx += 256) {
    int c = idx & 63; int rem = idx >> 6; int wc = rem % 18; int r = rem / 18;
    int hh = h - 1 + r, wg = wbase + wc - 1;
    float2 xv = make_float2(0.f, 0.f); float uv = 0.f;
    if (hh >= 0 && hh < NH && wg >= 0 && wg < NW) {
      size_t o = (size_t)(hh * NW + wg) * 64 + c;
      xv = xsrc[o]; uv = usrc[o];
    }
    xin[r][wc][c] = xv; uin[r][wc][c] = uv;
  }
  __syncthreads();
  int p = t & 63, wq = t >> 6;   // p = output channel u; w = wbase + wq*4 + k
  float acc[4] = {0.f, 0.f, 0.f, 0.f};
  for (int kh = 0; kh < 3; kh++)
    for (int kw = 0; kw < 3; kw++) {
      const float* cr = Cr + (size_t)((kh * 3 + kw) * 64) * 64 + p;
      const float* ci = Ci + (size_t)((kh * 3 + kw) * 64) * 64 + p;
      const float* dk = Dk + (size_t)((kh * 3 + kw) * 64) * 64 + p;
#pragma unroll 4
      for (int cin = 0; cin < 64; cin++) {
        float wcr =  2.f * cr[(size_t)cin * 64];
        float wci = -2.f * ci[(size_t)cin * 64];
        float wd  =        dk[(size_t)cin * 64];
#pragma unroll
        for (int k = 0; k < 4; k++) {
          float2 xv = xin[kh][wq * 4 + k + kw][cin];
          float uv  = uin[kh][wq * 4 + k + kw][cin];
          acc[k] = fmaf(xv.x, wcr, acc[k]);
          acc[k] = fmaf(xv.y, wci, acc[k]);
          acc[k] = fmaf(uv,  wd,  acc[k]);
        }
      }
    }
  size_t obase = (size_t)img * HWN * NU + (size_t)h * NW * NU;
#pragma unroll
  for (int k = 0; k < 4; k++) {
    int w = wbase + wq * 4 + k;
    float x = acc[k];
    float x3 = x * x * x;
    float tt = tanhf(0.7978845608028654f * (x + 0.044715f * x3));
    out[obase + (size_t)w * NU + p] = 0.5f * x * (1.f + tt);
  }
}

// ---------------------------------------------------------------------------
extern "C" void kernel_launch(void* const* d_in, const int* in_sizes, int n_in,
                              void* d_out, int out_size, void* d_ws, size_t ws_size,
                              hipStream_t stream) {
  const float* u        = (const float*)d_in[0];
  const float* x0       = (const float*)d_in[1];
  const float* Lre      = (const float*)d_in[2];
  const float* Lim      = (const float*)d_in[3];
  const float* values   = (const float*)d_in[4];
  const float* log_step = (const float*)d_in[5];
  const float* Br       = (const float*)d_in[6];
  const float* Bi       = (const float*)d_in[7];
  const float* Cr       = (const float*)d_in[8];
  const float* Ci       = (const float*)d_in[9];
  const float* Dk       = (const float*)d_in[10];
  float* out = (float*)d_out;

  // workspace layout (~133.5 MiB total):
  //   S: 4 KiB | kv: 4 KiB | A: 512 KiB | Bc: 512 KiB
  //   XBUF (264 imgs complex, reused through the whole pipeline): 132 MiB
  char* ws = (char*)d_ws;
  float*  S  = (float*)ws;
  float*  kv = (float*)(ws + 4096);
  float2* A  = (float2*)(ws + 8192);
  float2* Bc = (float2*)(ws + 8192 + 524288);
  float2* XBUF = (float2*)(ws + 8192 + 2 * 524288);

  hipLaunchKernelGGL(k_setup,   dim3(1),             dim3(1024), 0, stream, values, S, kv);
  hipLaunchKernelGGL(k_coeff,   dim3(256),           dim3(256),  0, stream, Lre, Lim, log_step, kv, A, Bc);
  hipLaunchKernelGGL(k_convB,   dim3(NIMG_TOT, 32),  dim3(256),  0, stream, u, x0, Br, Bi, XBUF);
  hipLaunchKernelGGL(k_dst_fwd, dim3(NIMG_TOT, 16),  dim3(256),  0, stream, XBUF, S, Bc);
  hipLaunchKernelGGL(k_scan,    dim3(2048),          dim3(256),  0, stream, A, XBUF);
  hipLaunchKernelGGL(k_dst_inv, dim3(NIMG, 16),      dim3(256),  0, stream, XBUF, S);
  hipLaunchKernelGGL(k_convCD,  dim3(NIMG, 32, 2),   dim3(256),  0, stream, XBUF, u, Cr, Ci, Dk, out);
}

// Round 3
// 1130.626 us; speedup vs baseline: 2.3138x; 2.3138x over previous
//
#include <hip/hip_runtime.h>
#include <cmath>

#ifndef M_PI
#define M_PI 3.14159265358979323846
#endif

#define NH 32
#define NW 32
#define NP 64
#define NU 64
#define NL 32
#define NB 8
#define NIMG 256
#define NIMG_TOT 264
#define HWN 1024
#define IMG_STRIDE 65536

typedef unsigned short u16;
typedef __bf16 bf16x8 __attribute__((ext_vector_type(8)));
typedef float f32x4 __attribute__((ext_vector_type(4)));

__device__ __forceinline__ u16 f2bf(float f) {
  unsigned u = __float_as_uint(f);
  u += 0x7fffu + ((u >> 16) & 1u);   // RNE
  return (u16)(u >> 16);
}
__device__ __forceinline__ float bf2f(u16 h) {
  return __uint_as_float(((unsigned)h) << 16);
}

// ---------------------------------------------------------------------------
// K0: S matrix (32x32 DST-I, real symmetric involutive) + kv from softmax
// ---------------------------------------------------------------------------
__global__ void k_setup(const float* __restrict__ values, float* __restrict__ S,
                        float* __restrict__ kv) {
  int t = threadIdx.x;
  int i = t >> 5, j = t & 31;
  double s = sin(M_PI * (double)((i + 1) * (j + 1)) / 33.0) / sqrt(16.5);
  S[t] = (float)s;
  if (t < NP) {
    float v0 = values[t * 4 + 0], v1 = values[t * 4 + 1];
    float v2 = values[t * 4 + 2], v3 = values[t * 4 + 3];
    float m = fmaxf(fmaxf(v0, v1), fmaxf(v2, v3));
    float e0 = expf(v0 - m), e1 = expf(v1 - m), e2 = expf(v2 - m), e3 = expf(v3 - m);
    float inv = 4.0f / (e0 + e1 + e2 + e3);
    float xk = e0 * inv, yk = e1 * inv, zk = e2 * inv, wk = e3 * inv;
    kv[t * 4 + 0] = (xk + yk - 2.0f) * 0.25f;
    kv[t * 4 + 1] = (xk + zk - 2.0f) * 0.25f;
    kv[t * 4 + 2] = (xk + wk - 2.0f) * 0.125f;
    kv[t * 4 + 3] = 0.f;
  }
}

// ---------------------------------------------------------------------------
// K1: A_bar, B_coeff in double
// ---------------------------------------------------------------------------
__global__ void k_coeff(const float* __restrict__ Lre, const float* __restrict__ Lim,
                        const float* __restrict__ log_step, const float* __restrict__ kv,
                        float2* __restrict__ A, float2* __restrict__ Bc) {
  int tid = blockIdx.x * blockDim.x + threadIdx.x;
  int n = tid >> 6, p = tid & 63;
  int h = n >> 5, w = n & 31;
  double ch = 2.0 * cos(M_PI * (double)(h + 1) / 33.0);
  double cw = 2.0 * cos(M_PI * (double)(w + 1) / 33.0);
  double Dv = (double)kv[p * 4 + 0] * cw + (double)kv[p * 4 + 1] * ch +
              (double)kv[p * 4 + 2] * ch * cw + 1.0;
  double lr = fmin((double)Lre[p], -0.0001);
  double li = (double)Lim[p];
  double tr = lr * Dv, ti = li * Dv;
  double st = exp((double)log_step[p]);
  double zr = tr * st, zi = ti * st;
  double ea = exp(zr);
  double Ar = ea * cos(zi), Ai = ea * sin(zi);
  double d = tr * tr + ti * ti;
  double br = ((Ar - 1.0) * tr + Ai * ti) / d;
  double bi = (Ai * tr - (Ar - 1.0) * ti) / d;
  A[tid]  = make_float2((float)Ar, (float)Ai);
  Bc[tid] = make_float2((float)br, (float)bi);
}

// ---------------------------------------------------------------------------
// K1b: pack conv weights into MFMA-fragment order, split bf16 hi/lo.
//  convB pack:  [kc 18][nt 8][lane 64][j 8], k = kc*32+(lane>>4)*8+j (0..575),
//               n = nt*16+(lane&15): n<64 -> Br, else Bi.
//  convCD pack: [kc 54][nt 4][lane 64][j 8], k = s*576+tap*64+c,
//               s=0: 2*Cr, s=1: -2*Ci, s=2: D.
// ---------------------------------------------------------------------------
#define NB_PACK (18 * 8 * 64 * 8)    // 73728
#define NC_PACK (54 * 4 * 64 * 8)    // 110592
__global__ __launch_bounds__(256) void k_pack(
    const float* __restrict__ Br, const float* __restrict__ Bi,
    const float* __restrict__ Cr, const float* __restrict__ Ci,
    const float* __restrict__ Dk,
    u16* __restrict__ WBhi, u16* __restrict__ WBlo,
    u16* __restrict__ WChi, u16* __restrict__ WClo) {
  int tid = blockIdx.x * 256 + threadIdx.x;
  if (tid < NB_PACK) {
    int j = tid & 7, lane = (tid >> 3) & 63, nt = (tid >> 9) & 7, kc = tid >> 12;
    int k = kc * 32 + ((lane >> 4) << 3) + j;
    int n = nt * 16 + (lane & 15);
    int tap = k >> 6, c = k & 63;
    float w = (n < 64) ? Br[(tap * 64 + c) * 64 + n]
                       : Bi[(tap * 64 + c) * 64 + (n - 64)];
    u16 hi = f2bf(w);
    WBhi[tid] = hi;
    WBlo[tid] = f2bf(w - bf2f(hi));
  } else {
    int t2 = tid - NB_PACK;
    if (t2 < NC_PACK) {
      int j = t2 & 7, lane = (t2 >> 3) & 63, nt = (t2 >> 9) & 3, kc = t2 >> 11;
      int k = kc * 32 + ((lane >> 4) << 3) + j;     // 0..1727
      int n = nt * 16 + (lane & 15);                 // 0..63
      int s = k / 576, rem = k % 576;
      int tap = rem >> 6, c = rem & 63;
      int widx = (tap * 64 + c) * 64 + n;
      float w = (s == 0) ? 2.f * Cr[widx] : (s == 1) ? -2.f * Ci[widx] : Dk[widx];
      u16 hi = f2bf(w);
      WChi[t2] = hi;
      WClo[t2] = f2bf(w - bf2f(hi));
    }
  }
}

// ---------------------------------------------------------------------------
// K2: convB via MFMA (split bf16, 3-term). Block: img x 4-row group.
//     M=128 pixels, N=128 (re0..63, im64..127), K=576 per split-term.
//     Wave wv: mgrp=wv>>1 (rows), ng=wv&1 (n-half). Writes XBUF with phase.
// ---------------------------------------------------------------------------
__global__ __launch_bounds__(256) void k_convB_mfma(
    const float* __restrict__ u, const float* __restrict__ x0,
    const u16* __restrict__ WBhi, const u16* __restrict__ WBlo,
    float2* __restrict__ XBUF) {
  __shared__ u16 lhs[6 * 34 * 72];
  __shared__ u16 lls[6 * 34 * 72];
  int img = blockIdx.x, h0 = blockIdx.y * 4;
  int t = threadIdx.x;
  const float* src = (img < NIMG) ? (u + (size_t)img * HWN * NU)
                                  : (x0 + (size_t)(img - NIMG) * HWN * NU);
  for (int idx = t; idx < 6 * 34 * 64; idx += 256) {
    int c = idx & 63, rem = idx >> 6, ww = rem % 34, r = rem / 34;
    int hh = h0 - 1 + r, wg = ww - 1;
    float v = 0.f;
    if (hh >= 0 && hh < NH && wg >= 0 && wg < NW) v = src[(hh * 32 + wg) * 64 + c];
    u16 hi = f2bf(v);
    int o = (r * 34 + ww) * 72 + c;
    lhs[o] = hi;
    lls[o] = f2bf(v - bf2f(hi));
  }
  __syncthreads();
  int lane = t & 63, wv = t >> 6;
  int mgrp = wv >> 1, ng = wv & 1;
  int l15 = lane & 15, l4 = lane >> 4;
  f32x4 acc[4][4];
#pragma unroll
  for (int i = 0; i < 4; i++)
#pragma unroll
    for (int q = 0; q < 4; q++) acc[i][q] = (f32x4){0.f, 0.f, 0.f, 0.f};

  for (int tap = 0; tap < 9; tap++) {
    int kh = tap / 3, kw = tap - kh * 3;
#pragma unroll
    for (int cc = 0; cc < 2; cc++) {
      int kc = tap * 2 + cc;
      bf16x8 ah[4], al[4], wh[4], wl[4];
#pragma unroll
      for (int mti = 0; mti < 4; mti++) {
        int row = mgrp * 2 + (mti >> 1);
        int off = ((row + kh) * 34 + (mti & 1) * 16 + l15 + kw) * 72 + cc * 32 + l4 * 8;
        ah[mti] = *(const bf16x8*)&lhs[off];
        al[mti] = *(const bf16x8*)&lls[off];
      }
#pragma unroll
      for (int q = 0; q < 4; q++) {
        int nt = ng * 2 + (q & 1) + (q >> 1) * 4;
        size_t woff = ((size_t)((kc * 8 + nt) * 64 + lane)) * 8;
        wh[q] = *(const bf16x8*)&WBhi[woff];
        wl[q] = *(const bf16x8*)&WBlo[woff];
      }
#pragma unroll
      for (int mti = 0; mti < 4; mti++)
#pragma unroll
        for (int q = 0; q < 4; q++) {
          f32x4 c = acc[mti][q];
          c = __builtin_amdgcn_mfma_f32_16x16x32_bf16(ah[mti], wh[q], c, 0, 0, 0);
          c = __builtin_amdgcn_mfma_f32_16x16x32_bf16(ah[mti], wl[q], c, 0, 0, 0);
          c = __builtin_amdgcn_mfma_f32_16x16x32_bf16(al[mti], wh[q], c, 0, 0, 0);
          acc[mti][q] = c;
        }
    }
  }
  // epilogue: apply (-i)^(h+w+2), store float2 [img][h][w][p]
  float2* dst = XBUF + (size_t)img * IMG_STRIDE;
#pragma unroll
  for (int mti = 0; mti < 4; mti++) {
    int h = h0 + mgrp * 2 + (mti >> 1);
#pragma unroll
    for (int half = 0; half < 2; half++) {
      int p = ng * 32 + half * 16 + l15;
#pragma unroll
      for (int reg = 0; reg < 4; reg++) {
        int wpix = (mti & 1) * 16 + l4 * 4 + reg;
        float re = acc[mti][half][reg];
        float im = acc[mti][2 + half][reg];
        int m = (h + wpix + 2) & 3;
        float2 o;
        if (m == 0)      o = make_float2( re,  im);
        else if (m == 1) o = make_float2( im, -re);
        else if (m == 2) o = make_float2(-re, -im);
        else             o = make_float2(-im,  re);
        dst[(h * 32 + wpix) * 64 + p] = o;
      }
    }
  }
}

// ---------------------------------------------------------------------------
// K3: forward DST IN-PLACE (unchanged from round 2)
// ---------------------------------------------------------------------------
__global__ __launch_bounds__(256) void k_dst_fwd(float2* __restrict__ XBUF,
                                                 const float* __restrict__ S,
                                                 const float2* __restrict__ Bc) {
  int img = blockIdx.x;
  int p0 = blockIdx.y * 4;
  __shared__ float2 tin[32][32][4];
  __shared__ float2 t1[32][32][4];
  int t = threadIdx.x;
  float2* base = XBUF + (size_t)img * IMG_STRIDE;
  for (int idx = t; idx < 4096; idx += 256) {
    int pp = idx & 3, w = (idx >> 2) & 31, hh = idx >> 7;
    tin[hh][w][pp] = base[(size_t)(hh * 32 + w) * 64 + p0 + pp];
  }
  __syncthreads();
  {
    int pp = t & 3, w = (t >> 2) & 31, a0 = t >> 7;
    for (int k = 0; k < 16; k++) {
      int a = a0 * 16 + k;
      float2 s = make_float2(0.f, 0.f);
#pragma unroll 8
      for (int hh = 0; hh < 32; hh++) {
        float sv = S[a * 32 + hh];
        float2 v = tin[hh][w][pp];
        s.x = fmaf(sv, v.x, s.x);
        s.y = fmaf(sv, v.y, s.y);
      }
      t1[a][w][pp] = s;
    }
  }
  __syncthreads();
  {
    int pp = t & 3, c = (t >> 2) & 31, a0 = t >> 7;
    for (int k = 0; k < 16; k++) {
      int a = a0 * 16 + k;
      float2 s = make_float2(0.f, 0.f);
#pragma unroll 8
      for (int w = 0; w < 32; w++) {
        float sv = S[c * 32 + w];
        float2 v = t1[a][w][pp];
        s.x = fmaf(sv, v.x, s.x);
        s.y = fmaf(sv, v.y, s.y);
      }
      int n = a * 32 + c;
      float2 bc = Bc[(size_t)n * 64 + p0 + pp];
      float2 o = make_float2(s.x * bc.x - s.y * bc.y, s.x * bc.y + s.y * bc.x);
      base[(size_t)n * 64 + p0 + pp] = o;
    }
  }
}

// ---------------------------------------------------------------------------
// K4: scan over l (unchanged)
// ---------------------------------------------------------------------------
__global__ __launch_bounds__(256) void k_scan(const float2* __restrict__ A,
                                              float2* __restrict__ X) {
  int gx = blockIdx.x;
  int b = gx >> 8, a = (gx >> 3) & 31, cg = gx & 7;
  int t = threadIdx.x;
  int c = cg * 4 + (t >> 6), p = t & 63;
  size_t off = (size_t)(a * 32 + c) * 64 + p;
  float2 Av = A[off];
  float2 x = X[(size_t)(NIMG + b) * IMG_STRIDE + off];
  for (int l = 0; l < NL; l++) {
    size_t idx = (size_t)(l * NB + b) * IMG_STRIDE + off;
    float2 v = X[idx];
    float2 nx;
    nx.x = Av.x * x.x - Av.y * x.y + v.x;
    nx.y = Av.x * x.y + Av.y * x.x + v.y;
    x = nx;
    X[idx] = x;
  }
}

// ---------------------------------------------------------------------------
// K5: inverse DST IN-PLACE (unchanged)
// ---------------------------------------------------------------------------
__global__ __launch_bounds__(256) void k_dst_inv(float2* __restrict__ XBUF,
                                                 const float* __restrict__ S) {
  int img = blockIdx.x;
  int p0 = blockIdx.y * 4;
  __shared__ float2 xin[32][32][4];
  __shared__ float2 t1[32][32][4];
  int t = threadIdx.x;
  float2* base = XBUF + (size_t)img * IMG_STRIDE;
  for (int idx = t; idx < 4096; idx += 256) {
    int pp = idx & 3, c = (idx >> 2) & 31, a = idx >> 7;
    xin[a][c][pp] = base[(size_t)(a * 32 + c) * 64 + p0 + pp];
  }
  __syncthreads();
  {
    int pp = t & 3, c = (t >> 2) & 31, h0 = t >> 7;
    for (int k = 0; k < 16; k++) {
      int h = h0 * 16 + k;
      float2 s = make_float2(0.f, 0.f);
#pragma unroll 8
      for (int a = 0; a < 32; a++) {
        float sv = S[h * 32 + a];
        float2 v = xin[a][c][pp];
        s.x = fmaf(sv, v.x, s.x);
        s.y = fmaf(sv, v.y, s.y);
      }
      t1[h][c][pp] = s;
    }
  }
  __syncthreads();
  {
    int pp = t & 3, w = (t >> 2) & 31, h0 = t >> 7;
    for (int k = 0; k < 16; k++) {
      int h = h0 * 16 + k;
      float2 s = make_float2(0.f, 0.f);
#pragma unroll 8
      for (int c = 0; c < 32; c++) {
        float sv = S[w * 32 + c];
        float2 v = t1[h][c][pp];
        s.x = fmaf(sv, v.x, s.x);
        s.y = fmaf(sv, v.y, s.y);
      }
      int m = (h + w + 2) & 3;
      float2 o;
      if (m == 0)      o = make_float2( s.x,  s.y);
      else if (m == 1) o = make_float2(-s.y,  s.x);
      else if (m == 2) o = make_float2(-s.x, -s.y);
      else             o = make_float2( s.y, -s.x);
      base[(size_t)(h * 32 + w) * 64 + p0 + pp] = o;
    }
  }
}

// ---------------------------------------------------------------------------
// K6: convCD via MFMA (split bf16, 3-term) + gelu.
//     M=128 pixels (4 rows), N=64, K=1728 (3 source planes staged seq.)
//     Wave wv: mgrp=wv>>1 (rows), ng=wv&1 (n-half).
// ---------------------------------------------------------------------------
__global__ __launch_bounds__(256) void k_convCD_mfma(
    const float2* __restrict__ XSP, const float* __restrict__ u,
    const u16* __restrict__ WChi, const u16* __restrict__ WClo,
    float* __restrict__ out) {
  __shared__ u16 lhs[6 * 34 * 72];
  __shared__ u16 lls[6 * 34 * 72];
  int img = blockIdx.x, h0 = blockIdx.y * 4;
  int t = threadIdx.x;
  int lane = t & 63, wv = t >> 6;
  int mgrp = wv >> 1, ng = wv & 1;
  int l15 = lane & 15, l4 = lane >> 4;
  const float2* xim = XSP + (size_t)img * IMG_STRIDE;
  const float* uim = u + (size_t)img * HWN * NU;
  f32x4 acc[4][2];
#pragma unroll
  for (int i = 0; i < 4; i++) {
    acc[i][0] = (f32x4){0.f, 0.f, 0.f, 0.f};
    acc[i][1] = (f32x4){0.f, 0.f, 0.f, 0.f};
  }

  for (int s = 0; s < 3; s++) {
    __syncthreads();
    for (int idx = t; idx < 6 * 34 * 64; idx += 256) {
      int c = idx & 63, rem = idx >> 6, ww = rem % 34, r = rem / 34;
      int hh = h0 - 1 + r, wg = ww - 1;
      float v = 0.f;
      if (hh >= 0 && hh < NH && wg >= 0 && wg < NW) {
        int o = (hh * 32 + wg) * 64 + c;
        v = (s == 0) ? xim[o].x : (s == 1) ? xim[o].y : uim[o];
      }
      u16 hi = f2bf(v);
      int o2 = (r * 34 + ww) * 72 + c;
      lhs[o2] = hi;
      lls[o2] = f2bf(v - bf2f(hi));
    }
    __syncthreads();
    for (int tap = 0; tap < 9; tap++) {
      int kh = tap / 3, kw = tap - kh * 3;
#pragma unroll
      for (int cc = 0; cc < 2; cc++) {
        int kc = (s * 9 + tap) * 2 + cc;
        bf16x8 ah[4], al[4], wh[2], wl[2];
#pragma unroll
        for (int mti = 0; mti < 4; mti++) {
          int row = mgrp * 2 + (mti >> 1);
          int off = ((row + kh) * 34 + (mti & 1) * 16 + l15 + kw) * 72 + cc * 32 + l4 * 8;
          ah[mti] = *(const bf16x8*)&lhs[off];
          al[mti] = *(const bf16x8*)&lls[off];
        }
#pragma unroll
        for (int q = 0; q < 2; q++) {
          int nt = ng * 2 + q;
          size_t woff = ((size_t)((kc * 4 + nt) * 64 + lane)) * 8;
          wh[q] = *(const bf16x8*)&WChi[woff];
          wl[q] = *(const bf16x8*)&WClo[woff];
        }
#pragma unroll
        for (int mti = 0; mti < 4; mti++)
#pragma unroll
          for (int q = 0; q < 2; q++) {
            f32x4 c = acc[mti][q];
            c = __builtin_amdgcn_mfma_f32_16x16x32_bf16(ah[mti], wh[q], c, 0, 0, 0);
            c = __builtin_amdgcn_mfma_f32_16x16x32_bf16(ah[mti], wl[q], c, 0, 0, 0);
            c = __builtin_amdgcn_mfma_f32_16x16x32_bf16(al[mti], wh[q], c, 0, 0, 0);
            acc[mti][q] = c;
          }
      }
    }
  }
  // epilogue: gelu + store
  float* dst = out + (size_t)img * HWN * NU;
#pragma unroll
  for (int mti = 0; mti < 4; mti++) {
    int h = h0 + mgrp * 2 + (mti >> 1);
#pragma unroll
    for (int q = 0; q < 2; q++) {
      int un = (ng * 2 + q) * 16 + l15;
#pragma unroll
      for (int reg = 0; reg < 4; reg++) {
        int wpix = (mti & 1) * 16 + l4 * 4 + reg;
        float x = acc[mti][q][reg];
        float z = 0.7978845608028654f * (x + 0.044715f * x * x * x);
        float e = __expf(2.f * z);
        float th = 1.f - 2.f / (e + 1.f);
        dst[(h * 32 + wpix) * 64 + un] = 0.5f * x * (1.f + th);
      }
    }
  }
}

// ---------------------------------------------------------------------------
extern "C" void kernel_launch(void* const* d_in, const int* in_sizes, int n_in,
                              void* d_out, int out_size, void* d_ws, size_t ws_size,
                              hipStream_t stream) {
  const float* u        = (const float*)d_in[0];
  const float* x0       = (const float*)d_in[1];
  const float* Lre      = (const float*)d_in[2];
  const float* Lim      = (const float*)d_in[3];
  const float* values   = (const float*)d_in[4];
  const float* log_step = (const float*)d_in[5];
  const float* Br       = (const float*)d_in[6];
  const float* Bi       = (const float*)d_in[7];
  const float* Cr       = (const float*)d_in[8];
  const float* Ci       = (const float*)d_in[9];
  const float* Dk       = (const float*)d_in[10];
  float* out = (float*)d_out;

  // workspace (~133.7 MiB): S 4K | kv 4K | A 512K | Bc 512K |
  //   WBhi/WBlo 144K each | WChi/WClo 216K each | XBUF 132M
  char* ws = (char*)d_ws;
  float*  S    = (float*)ws;                       ws += 4096;
  float*  kv   = (float*)ws;                       ws += 4096;
  float2* A    = (float2*)ws;                      ws += 524288;
  float2* Bc   = (float2*)ws;                      ws += 524288;
  u16*    WBhi = (u16*)ws;                         ws += NB_PACK * 2;
  u16*    WBlo = (u16*)ws;                         ws += NB_PACK * 2;
  u16*    WChi = (u16*)ws;                         ws += NC_PACK * 2;
  u16*    WClo = (u16*)ws;                         ws += NC_PACK * 2;
  float2* XBUF = (float2*)ws;

  hipLaunchKernelGGL(k_setup,      dim3(1),            dim3(1024), 0, stream, values, S, kv);
  hipLaunchKernelGGL(k_coeff,      dim3(256),          dim3(256),  0, stream, Lre, Lim, log_step, kv, A, Bc);
  hipLaunchKernelGGL(k_pack,       dim3(720),          dim3(256),  0, stream, Br, Bi, Cr, Ci, Dk, WBhi, WBlo, WChi, WClo);
  hipLaunchKernelGGL(k_convB_mfma, dim3(NIMG_TOT, 8),  dim3(256),  0, stream, u, x0, WBhi, WBlo, XBUF);
  hipLaunchKernelGGL(k_dst_fwd,    dim3(NIMG_TOT, 16), dim3(256),  0, stream, XBUF, S, Bc);
  hipLaunchKernelGGL(k_scan,       dim3(2048),         dim3(256),  0, stream, A, XBUF);
  hipLaunchKernelGGL(k_dst_inv,    dim3(NIMG, 16),     dim3(256),  0, stream, XBUF, S);
  hipLaunchKernelGGL(k_convCD_mfma,dim3(NIMG, 8),      dim3(256),  0, stream, XBUF, u, WChi, WClo, out);
}

// Round 4
// 914.044 us; speedup vs baseline: 2.8621x; 1.2369x over previous
//
#include <hip/hip_runtime.h>
#include <cmath>

#ifndef M_PI
#define M_PI 3.14159265358979323846
#endif

#define NH 32
#define NW 32
#define NP 64
#define NU 64
#define NL 32
#define NB 8
#define NIMG 256
#define NIMG_TOT 264
#define HWN 1024
#define IMG_STRIDE 65536          // float2 elements per image region
#define IMG_U16 262144            // u16 elements per image region (same bytes)

typedef unsigned short u16;
typedef __bf16 bf16x8 __attribute__((ext_vector_type(8)));
typedef float f32x4 __attribute__((ext_vector_type(4)));

__device__ __forceinline__ u16 f2bf(float f) {
  unsigned u = __float_as_uint(f);
  u += 0x7fffu + ((u >> 16) & 1u);   // RNE
  return (u16)(u >> 16);
}
__device__ __forceinline__ float bf2f(u16 h) {
  return __uint_as_float(((unsigned)h) << 16);
}

// ---------------------------------------------------------------------------
// K0: S matrix (32x32 DST-I, real symmetric involutive) + kv from softmax
// ---------------------------------------------------------------------------
__global__ void k_setup(const float* __restrict__ values, float* __restrict__ S,
                        float* __restrict__ kv) {
  int t = threadIdx.x;
  int i = t >> 5, j = t & 31;
  double s = sin(M_PI * (double)((i + 1) * (j + 1)) / 33.0) / sqrt(16.5);
  S[t] = (float)s;
  if (t < NP) {
    float v0 = values[t * 4 + 0], v1 = values[t * 4 + 1];
    float v2 = values[t * 4 + 2], v3 = values[t * 4 + 3];
    float m = fmaxf(fmaxf(v0, v1), fmaxf(v2, v3));
    float e0 = expf(v0 - m), e1 = expf(v1 - m), e2 = expf(v2 - m), e3 = expf(v3 - m);
    float inv = 4.0f / (e0 + e1 + e2 + e3);
    float xk = e0 * inv, yk = e1 * inv, zk = e2 * inv, wk = e3 * inv;
    kv[t * 4 + 0] = (xk + yk - 2.0f) * 0.25f;
    kv[t * 4 + 1] = (xk + zk - 2.0f) * 0.25f;
    kv[t * 4 + 2] = (xk + wk - 2.0f) * 0.125f;
    kv[t * 4 + 3] = 0.f;
  }
}

// ---------------------------------------------------------------------------
// K1: A_bar, B_coeff in double
// ---------------------------------------------------------------------------
__global__ void k_coeff(const float* __restrict__ Lre, const float* __restrict__ Lim,
                        const float* __restrict__ log_step, const float* __restrict__ kv,
                        float2* __restrict__ A, float2* __restrict__ Bc) {
  int tid = blockIdx.x * blockDim.x + threadIdx.x;
  int n = tid >> 6, p = tid & 63;
  int h = n >> 5, w = n & 31;
  double ch = 2.0 * cos(M_PI * (double)(h + 1) / 33.0);
  double cw = 2.0 * cos(M_PI * (double)(w + 1) / 33.0);
  double Dv = (double)kv[p * 4 + 0] * cw + (double)kv[p * 4 + 1] * ch +
              (double)kv[p * 4 + 2] * ch * cw + 1.0;
  double lr = fmin((double)Lre[p], -0.0001);
  double li = (double)Lim[p];
  double tr = lr * Dv, ti = li * Dv;
  double st = exp((double)log_step[p]);
  double zr = tr * st, zi = ti * st;
  double ea = exp(zr);
  double Ar = ea * cos(zi), Ai = ea * sin(zi);
  double d = tr * tr + ti * ti;
  double br = ((Ar - 1.0) * tr + Ai * ti) / d;
  double bi = (Ai * tr - (Ar - 1.0) * ti) / d;
  A[tid]  = make_float2((float)Ar, (float)Ai);
  Bc[tid] = make_float2((float)br, (float)bi);
}

// ---------------------------------------------------------------------------
// K1b: pack conv weights into MFMA-fragment order, split bf16 hi/lo.
// ---------------------------------------------------------------------------
#define NB_PACK (18 * 8 * 64 * 8)    // 73728
#define NC_PACK (54 * 4 * 64 * 8)    // 110592
__global__ __launch_bounds__(256) void k_pack(
    const float* __restrict__ Br, const float* __restrict__ Bi,
    const float* __restrict__ Cr, const float* __restrict__ Ci,
    const float* __restrict__ Dk,
    u16* __restrict__ WBhi, u16* __restrict__ WBlo,
    u16* __restrict__ WChi, u16* __restrict__ WClo) {
  int tid = blockIdx.x * 256 + threadIdx.x;
  if (tid < NB_PACK) {
    int j = tid & 7, lane = (tid >> 3) & 63, nt = (tid >> 9) & 7, kc = tid >> 12;
    int k = kc * 32 + ((lane >> 4) << 3) + j;
    int n = nt * 16 + (lane & 15);
    int tap = k >> 6, c = k & 63;
    float w = (n < 64) ? Br[(tap * 64 + c) * 64 + n]
                       : Bi[(tap * 64 + c) * 64 + (n - 64)];
    u16 hi = f2bf(w);
    WBhi[tid] = hi;
    WBlo[tid] = f2bf(w - bf2f(hi));
  } else {
    int t2 = tid - NB_PACK;
    if (t2 < NC_PACK) {
      int j = t2 & 7, lane = (t2 >> 3) & 63, nt = (t2 >> 9) & 3, kc = t2 >> 11;
      int k = kc * 32 + ((lane >> 4) << 3) + j;     // 0..1727
      int n = nt * 16 + (lane & 15);                 // 0..63
      int s = k / 576, rem = k % 576;
      int tap = rem >> 6, c = rem & 63;
      int widx = (tap * 64 + c) * 64 + n;
      float w = (s == 0) ? 2.f * Cr[widx] : (s == 1) ? -2.f * Ci[widx] : Dk[widx];
      u16 hi = f2bf(w);
      WChi[t2] = hi;
      WClo[t2] = f2bf(w - bf2f(hi));
    }
  }
}

// ---------------------------------------------------------------------------
// K2: convB via MFMA. LDS: 64-stride + XOR swizzle (52,224 B -> 3 blocks/CU).
// ---------------------------------------------------------------------------
__global__ __launch_bounds__(256) void k_convB_mfma(
    const float* __restrict__ u, const float* __restrict__ x0,
    const u16* __restrict__ WBhi, const u16* __restrict__ WBlo,
    float2* __restrict__ XBUF) {
  __shared__ u16 lhs[6 * 34 * 64];
  __shared__ u16 lls[6 * 34 * 64];
  int img = blockIdx.x, h0 = blockIdx.y * 4;
  int t = threadIdx.x;
  const float* src = (img < NIMG) ? (u + (size_t)img * HWN * NU)
                                  : (x0 + (size_t)(img - NIMG) * HWN * NU);
  // stage u (f32 -> hi/lo bf16), float4-vectorized, 3264/256 ~ 13 iters
  for (int idx = t; idx < 6 * 34 * 16; idx += 256) {
    int c4 = idx & 15, rem = idx >> 4, w = rem % 34, r = rem / 34;
    int hh = h0 - 1 + r, wg = w - 1;
    float4 v = make_float4(0.f, 0.f, 0.f, 0.f);
    if (hh >= 0 && hh < NH && wg >= 0 && wg < NW)
      v = *(const float4*)(src + (hh * 32 + wg) * 64 + c4 * 4);
    u16 a0 = f2bf(v.x), a1 = f2bf(v.y), a2 = f2bf(v.z), a3 = f2bf(v.w);
    u16 b0 = f2bf(v.x - bf2f(a0)), b1 = f2bf(v.y - bf2f(a1));
    u16 b2 = f2bf(v.z - bf2f(a2)), b3 = f2bf(v.w - bf2f(a3));
    int a = (r * 34 + w) * 64 + (((c4 >> 1) ^ (w & 7)) << 3) + ((c4 & 1) << 2);
    *(ushort4*)&lhs[a] = make_ushort4(a0, a1, a2, a3);
    *(ushort4*)&lls[a] = make_ushort4(b0, b1, b2, b3);
  }
  __syncthreads();
  int lane = t & 63, wv = t >> 6;
  int mgrp = wv >> 1, ng = wv & 1;
  int l15 = lane & 15, l4 = lane >> 4;
  f32x4 acc[4][4];
#pragma unroll
  for (int i = 0; i < 4; i++)
#pragma unroll
    for (int q = 0; q < 4; q++) acc[i][q] = (f32x4){0.f, 0.f, 0.f, 0.f};

  for (int tap = 0; tap < 9; tap++) {
    int kh = tap / 3, kw = tap - kh * 3;
#pragma unroll
    for (int cc = 0; cc < 2; cc++) {
      int kc = tap * 2 + cc;
      bf16x8 ah[4], al[4], wh[4], wl[4];
#pragma unroll
      for (int mti = 0; mti < 4; mti++) {
        int row = mgrp * 2 + (mti >> 1);
        int wt = (mti & 1) * 16 + l15 + kw;
        int off = ((row + kh) * 34 + wt) * 64 + (((cc * 4 + l4) ^ (wt & 7)) << 3);
        ah[mti] = *(const bf16x8*)&lhs[off];
        al[mti] = *(const bf16x8*)&lls[off];
      }
#pragma unroll
      for (int q = 0; q < 4; q++) {
        int nt = ng * 2 + (q & 1) + (q >> 1) * 4;
        size_t woff = ((size_t)((kc * 8 + nt) * 64 + lane)) * 8;
        wh[q] = *(const bf16x8*)&WBhi[woff];
        wl[q] = *(const bf16x8*)&WBlo[woff];
      }
#pragma unroll
      for (int mti = 0; mti < 4; mti++)
#pragma unroll
        for (int q = 0; q < 4; q++) {
          f32x4 c = acc[mti][q];
          c = __builtin_amdgcn_mfma_f32_16x16x32_bf16(ah[mti], wh[q], c, 0, 0, 0);
          c = __builtin_amdgcn_mfma_f32_16x16x32_bf16(ah[mti], wl[q], c, 0, 0, 0);
          c = __builtin_amdgcn_mfma_f32_16x16x32_bf16(al[mti], wh[q], c, 0, 0, 0);
          acc[mti][q] = c;
        }
    }
  }
  float2* dst = XBUF + (size_t)img * IMG_STRIDE;
#pragma unroll
  for (int mti = 0; mti < 4; mti++) {
    int h = h0 + mgrp * 2 + (mti >> 1);
#pragma unroll
    for (int half = 0; half < 2; half++) {
      int p = ng * 32 + half * 16 + l15;
#pragma unroll
      for (int reg = 0; reg < 4; reg++) {
        int wpix = (mti & 1) * 16 + l4 * 4 + reg;
        float re = acc[mti][half][reg];
        float im = acc[mti][2 + half][reg];
        int m = (h + wpix + 2) & 3;
        float2 o;
        if (m == 0)      o = make_float2( re,  im);
        else if (m == 1) o = make_float2( im, -re);
        else if (m == 2) o = make_float2(-re, -im);
        else             o = make_float2(-im,  re);
        dst[(h * 32 + wpix) * 64 + p] = o;
      }
    }
  }
}

// ---------------------------------------------------------------------------
// K3: forward DST IN-PLACE (unchanged)
// ---------------------------------------------------------------------------
__global__ __launch_bounds__(256) void k_dst_fwd(float2* __restrict__ XBUF,
                                                 const float* __restrict__ S,
                                                 const float2* __restrict__ Bc) {
  int img = blockIdx.x;
  int p0 = blockIdx.y * 4;
  __shared__ float2 tin[32][32][4];
  __shared__ float2 t1[32][32][4];
  int t = threadIdx.x;
  float2* base = XBUF + (size_t)img * IMG_STRIDE;
  for (int idx = t; idx < 4096; idx += 256) {
    int pp = idx & 3, w = (idx >> 2) & 31, hh = idx >> 7;
    tin[hh][w][pp] = base[(size_t)(hh * 32 + w) * 64 + p0 + pp];
  }
  __syncthreads();
  {
    int pp = t & 3, w = (t >> 2) & 31, a0 = t >> 7;
    for (int k = 0; k < 16; k++) {
      int a = a0 * 16 + k;
      float2 s = make_float2(0.f, 0.f);
#pragma unroll 8
      for (int hh = 0; hh < 32; hh++) {
        float sv = S[a * 32 + hh];
        float2 v = tin[hh][w][pp];
        s.x = fmaf(sv, v.x, s.x);
        s.y = fmaf(sv, v.y, s.y);
      }
      t1[a][w][pp] = s;
    }
  }
  __syncthreads();
  {
    int pp = t & 3, c = (t >> 2) & 31, a0 = t >> 7;
    for (int k = 0; k < 16; k++) {
      int a = a0 * 16 + k;
      float2 s = make_float2(0.f, 0.f);
#pragma unroll 8
      for (int w = 0; w < 32; w++) {
        float sv = S[c * 32 + w];
        float2 v = t1[a][w][pp];
        s.x = fmaf(sv, v.x, s.x);
        s.y = fmaf(sv, v.y, s.y);
      }
      int n = a * 32 + c;
      float2 bc = Bc[(size_t)n * 64 + p0 + pp];
      float2 o = make_float2(s.x * bc.x - s.y * bc.y, s.x * bc.y + s.y * bc.x);
      base[(size_t)n * 64 + p0 + pp] = o;
    }
  }
}

// ---------------------------------------------------------------------------
// K4: scan over l (unchanged)
// ---------------------------------------------------------------------------
__global__ __launch_bounds__(256) void k_scan(const float2* __restrict__ A,
                                              float2* __restrict__ X) {
  int gx = blockIdx.x;
  int b = gx >> 8, a = (gx >> 3) & 31, cg = gx & 7;
  int t = threadIdx.x;
  int c = cg * 4 + (t >> 6), p = t & 63;
  size_t off = (size_t)(a * 32 + c) * 64 + p;
  float2 Av = A[off];
  float2 x = X[(size_t)(NIMG + b) * IMG_STRIDE + off];
  for (int l = 0; l < NL; l++) {
    size_t idx = (size_t)(l * NB + b) * IMG_STRIDE + off;
    float2 v = X[idx];
    float2 nx;
    nx.x = Av.x * x.x - Av.y * x.y + v.x;
    nx.y = Av.x * x.y + Av.y * x.x + v.y;
    x = nx;
    X[idx] = x;
  }
}

// ---------------------------------------------------------------------------
// K5: inverse DST, IN-PLACE format change: reads spectral float2, writes
//     chunked bf16 planes into the SAME bytes. For p-chunk pc, spatial pixel
//     n = h*32+w: 32-B slot at u16 offset n*256 + pc*16 holds
//     [xr_hi(4pp), xr_lo(4pp), xi_hi(4pp), xi_lo(4pp)] — exactly the bytes of
//     float2 elements n*64 + pc*4 .. +3, so each block rewrites only the bytes
//     it read (cross-block disjoint, in-block LDS-buffered => race-free).
// ---------------------------------------------------------------------------
__global__ __launch_bounds__(256) void k_dst_inv(float2* __restrict__ XBUF,
                                                 const float* __restrict__ S) {
  int img = blockIdx.x;
  int pc = blockIdx.y;
  int p0 = pc * 4;
  __shared__ float2 xin[32][32][4];   // stage-1 input; reused as u16 mirror later
  __shared__ float2 t1[32][32][4];
  int t = threadIdx.x;
  float2* base = XBUF + (size_t)img * IMG_STRIDE;
  for (int idx = t; idx < 4096; idx += 256) {
    int pp = idx & 3, c = (idx >> 2) & 31, a = idx >> 7;
    xin[a][c][pp] = base[(size_t)(a * 32 + c) * 64 + p0 + pp];
  }
  __syncthreads();
  {
    int pp = t & 3, c = (t >> 2) & 31, hg = t >> 7;
    for (int k = 0; k < 16; k++) {
      int h = hg * 16 + k;
      float2 s = make_float2(0.f, 0.f);
#pragma unroll 8
      for (int a = 0; a < 32; a++) {
        float sv = S[h * 32 + a];
        float2 v = xin[a][c][pp];
        s.x = fmaf(sv, v.x, s.x);
        s.y = fmaf(sv, v.y, s.y);
      }
      t1[h][c][pp] = s;
    }
  }
  __syncthreads();
  u16* mir = (u16*)xin;   // 32 KB mirror of this (img, pc) chunk's slots
  {
    int pp = t & 3, w = (t >> 2) & 31, hg = t >> 7;
    for (int k = 0; k < 16; k++) {
      int h = hg * 16 + k;
      float2 s = make_float2(0.f, 0.f);
#pragma unroll 8
      for (int c = 0; c < 32; c++) {
        float sv = S[w * 32 + c];
        float2 v = t1[h][c][pp];
        s.x = fmaf(sv, v.x, s.x);
        s.y = fmaf(sv, v.y, s.y);
      }
      int m = (h + w + 2) & 3;
      float2 o;
      if (m == 0)      o = make_float2( s.x,  s.y);
      else if (m == 1) o = make_float2(-s.y,  s.x);
      else if (m == 2) o = make_float2(-s.x, -s.y);
      else             o = make_float2( s.y, -s.x);
      u16 hr = f2bf(o.x), lr = f2bf(o.x - bf2f(hr));
      u16 hm = f2bf(o.y), lm = f2bf(o.y - bf2f(hm));
      int mb = (h * 32 + w) * 16 + pp;
      mir[mb]      = hr;
      mir[mb + 4]  = lr;
      mir[mb + 8]  = hm;
      mir[mb + 12] = lm;
    }
  }
  __syncthreads();
  {
    const uint4* msrc = (const uint4*)mir;      // 2048 x 16B
    u16* gb = (u16*)base;
    for (int c = t; c < 2048; c += 256) {
      int n = c >> 1, half = c & 1;
      *(uint4*)(gb + n * 256 + pc * 16 + half * 8) = msrc[c];
    }
  }
}

// ---------------------------------------------------------------------------
// K6: convCD via MFMA + gelu. xr/xi staged from pre-split chunked planes
//     (pure 16B copies); u staged f32->split. LDS 52,224 B -> 3 blocks/CU.
// ---------------------------------------------------------------------------
__global__ __launch_bounds__(256) void k_convCD_mfma(
    const u16* __restrict__ XP,      // XBUF viewed as chunked planes
    const float* __restrict__ u,
    const u16* __restrict__ WChi, const u16* __restrict__ WClo,
    float* __restrict__ out) {
  __shared__ u16 lhs[6 * 34 * 64];
  __shared__ u16 lls[6 * 34 * 64];
  int img = blockIdx.x, h0 = blockIdx.y * 4;
  int t = threadIdx.x;
  int lane = t & 63, wv = t >> 6;
  int mgrp = wv >> 1, ng = wv & 1;
  int l15 = lane & 15, l4 = lane >> 4;
  const u16* xim = XP + (size_t)img * IMG_U16;
  const float* uim = u + (size_t)img * HWN * NU;
  f32x4 acc[4][2];
#pragma unroll
  for (int i = 0; i < 4; i++) {
    acc[i][0] = (f32x4){0.f, 0.f, 0.f, 0.f};
    acc[i][1] = (f32x4){0.f, 0.f, 0.f, 0.f};
  }

  for (int s = 0; s < 3; s++) {
    __syncthreads();
    if (s < 2) {
      // hi+lo of xr (s=0) or xi (s=1): one 16B load per (r,w,pc)
      for (int idx = t; idx < 6 * 34 * 16; idx += 256) {
        int pc = idx & 15, rem = idx >> 4, w = rem % 34, r = rem / 34;
        int hh = h0 - 1 + r, wg = w - 1;
        uint4 d = make_uint4(0u, 0u, 0u, 0u);
        if (hh >= 0 && hh < NH && wg >= 0 && wg < NW)
          d = *(const uint4*)(xim + (hh * 32 + wg) * 256 + pc * 16 + s * 8);
        int a = (r * 34 + w) * 64 + (((pc >> 1) ^ (w & 7)) << 3) + ((pc & 1) << 2);
        *(uint2*)&lhs[a] = make_uint2(d.x, d.y);
        *(uint2*)&lls[a] = make_uint2(d.z, d.w);
      }
    } else {
      for (int idx = t; idx < 6 * 34 * 16; idx += 256) {
        int c4 = idx & 15, rem = idx >> 4, w = rem % 34, r = rem / 34;
        int hh = h0 - 1 + r, wg = w - 1;
        float4 v = make_float4(0.f, 0.f, 0.f, 0.f);
        if (hh >= 0 && hh < NH && wg >= 0 && wg < NW)
          v = *(const float4*)(uim + (hh * 32 + wg) * 64 + c4 * 4);
        u16 a0 = f2bf(v.x), a1 = f2bf(v.y), a2 = f2bf(v.z), a3 = f2bf(v.w);
        u16 b0 = f2bf(v.x - bf2f(a0)), b1 = f2bf(v.y - bf2f(a1));
        u16 b2 = f2bf(v.z - bf2f(a2)), b3 = f2bf(v.w - bf2f(a3));
        int a = (r * 34 + w) * 64 + (((c4 >> 1) ^ (w & 7)) << 3) + ((c4 & 1) << 2);
        *(ushort4*)&lhs[a] = make_ushort4(a0, a1, a2, a3);
        *(ushort4*)&lls[a] = make_ushort4(b0, b1, b2, b3);
      }
    }
    __syncthreads();
    for (int tap = 0; tap < 9; tap++) {
      int kh = tap / 3, kw = tap - kh * 3;
#pragma unroll
      for (int cc = 0; cc < 2; cc++) {
        int kc = (s * 9 + tap) * 2 + cc;
        bf16x8 ah[4], al[4], wh[2], wl[2];
#pragma unroll
        for (int mti = 0; mti < 4; mti++) {
          int row = mgrp * 2 + (mti >> 1);
          int wt = (mti & 1) * 16 + l15 + kw;
          int off = ((row + kh) * 34 + wt) * 64 + (((cc * 4 + l4) ^ (wt & 7)) << 3);
          ah[mti] = *(const bf16x8*)&lhs[off];
          al[mti] = *(const bf16x8*)&lls[off];
        }
#pragma unroll
        for (int q = 0; q < 2; q++) {
          int nt = ng * 2 + q;
          size_t woff = ((size_t)((kc * 4 + nt) * 64 + lane)) * 8;
          wh[q] = *(const bf16x8*)&WChi[woff];
          wl[q] = *(const bf16x8*)&WClo[woff];
        }
#pragma unroll
        for (int mti = 0; mti < 4; mti++)
#pragma unroll
          for (int q = 0; q < 2; q++) {
            f32x4 c = acc[mti][q];
            c = __builtin_amdgcn_mfma_f32_16x16x32_bf16(ah[mti], wh[q], c, 0, 0, 0);
            c = __builtin_amdgcn_mfma_f32_16x16x32_bf16(ah[mti], wl[q], c, 0, 0, 0);
            c = __builtin_amdgcn_mfma_f32_16x16x32_bf16(al[mti], wh[q], c, 0, 0, 0);
            acc[mti][q] = c;
          }
      }
    }
  }
  float* dst = out + (size_t)img * HWN * NU;
#pragma unroll
  for (int mti = 0; mti < 4; mti++) {
    int h = h0 + mgrp * 2 + (mti >> 1);
#pragma unroll
    for (int q = 0; q < 2; q++) {
      int un = (ng * 2 + q) * 16 + l15;
#pragma unroll
      for (int reg = 0; reg < 4; reg++) {
        int wpix = (mti & 1) * 16 + l4 * 4 + reg;
        float x = acc[mti][q][reg];
        float z = 0.7978845608028654f * (x + 0.044715f * x * x * x);
        float e = __expf(2.f * z);
        float th = 1.f - 2.f / (e + 1.f);
        dst[(h * 32 + wpix) * 64 + un] = 0.5f * x * (1.f + th);
      }
    }
  }
}

// ---------------------------------------------------------------------------
extern "C" void kernel_launch(void* const* d_in, const int* in_sizes, int n_in,
                              void* d_out, int out_size, void* d_ws, size_t ws_size,
                              hipStream_t stream) {
  const float* u        = (const float*)d_in[0];
  const float* x0       = (const float*)d_in[1];
  const float* Lre      = (const float*)d_in[2];
  const float* Lim      = (const float*)d_in[3];
  const float* values   = (const float*)d_in[4];
  const float* log_step = (const float*)d_in[5];
  const float* Br       = (const float*)d_in[6];
  const float* Bi       = (const float*)d_in[7];
  const float* Cr       = (const float*)d_in[8];
  const float* Ci       = (const float*)d_in[9];
  const float* Dk       = (const float*)d_in[10];
  float* out = (float*)d_out;

  // workspace (~133.7 MiB): S 4K | kv 4K | A 512K | Bc 512K |
  //   WBhi/WBlo 144K each | WChi/WClo 216K each | XBUF 132M
  char* ws = (char*)d_ws;
  float*  S    = (float*)ws;                       ws += 4096;
  float*  kv   = (float*)ws;                       ws += 4096;
  float2* A    = (float2*)ws;                      ws += 524288;
  float2* Bc   = (float2*)ws;                      ws += 524288;
  u16*    WBhi = (u16*)ws;                         ws += NB_PACK * 2;
  u16*    WBlo = (u16*)ws;                         ws += NB_PACK * 2;
  u16*    WChi = (u16*)ws;                         ws += NC_PACK * 2;
  u16*    WClo = (u16*)ws;                         ws += NC_PACK * 2;
  float2* XBUF = (float2*)ws;

  hipLaunchKernelGGL(k_setup,      dim3(1),            dim3(1024), 0, stream, values, S, kv);
  hipLaunchKernelGGL(k_coeff,      dim3(256),          dim3(256),  0, stream, Lre, Lim, log_step, kv, A, Bc);
  hipLaunchKernelGGL(k_pack,       dim3(720),          dim3(256),  0, stream, Br, Bi, Cr, Ci, Dk, WBhi, WBlo, WChi, WClo);
  hipLaunchKernelGGL(k_convB_mfma, dim3(NIMG_TOT, 8),  dim3(256),  0, stream, u, x0, WBhi, WBlo, XBUF);
  hipLaunchKernelGGL(k_dst_fwd,    dim3(NIMG_TOT, 16), dim3(256),  0, stream, XBUF, S, Bc);
  hipLaunchKernelGGL(k_scan,       dim3(2048),         dim3(256),  0, stream, A, XBUF);
  hipLaunchKernelGGL(k_dst_inv,    dim3(NIMG, 16),     dim3(256),  0, stream, XBUF, S);
  hipLaunchKernelGGL(k_convCD_mfma,dim3(NIMG, 8),      dim3(256),  0, stream, (const u16*)XBUF, u, WChi, WClo, out);
}

// Round 5
// 825.798 us; speedup vs baseline: 3.1679x; 1.1069x over previous
//
#include <hip/hip_runtime.h>
#include <cmath>

#ifndef M_PI
#define M_PI 3.14159265358979323846
#endif

#define NH 32
#define NW 32
#define NP 64
#define NU 64
#define NL 32
#define NB 8
#define NIMG 256
#define NIMG_TOT 264
#define HWN 1024
#define IMG_STRIDE 65536          // float2 elements per image region

typedef unsigned short u16;
typedef unsigned int u32;
typedef __bf16 bf16x8 __attribute__((ext_vector_type(8)));
typedef float f32x4 __attribute__((ext_vector_type(4)));

__device__ __forceinline__ u16 f2bf(float f) {
  unsigned u = __float_as_uint(f);
  u += 0x7fffu + ((u >> 16) & 1u);   // RNE
  return (u16)(u >> 16);
}
__device__ __forceinline__ float bf2f(u16 h) {
  return __uint_as_float(((unsigned)h) << 16);
}

// ---------------------------------------------------------------------------
// K0: S matrix (32x32 DST-I, real symmetric involutive) + kv from softmax
// ---------------------------------------------------------------------------
__global__ void k_setup(const float* __restrict__ values, float* __restrict__ S,
                        float* __restrict__ kv) {
  int t = threadIdx.x;
  int i = t >> 5, j = t & 31;
  double s = sin(M_PI * (double)((i + 1) * (j + 1)) / 33.0) / sqrt(16.5);
  S[t] = (float)s;
  if (t < NP) {
    float v0 = values[t * 4 + 0], v1 = values[t * 4 + 1];
    float v2 = values[t * 4 + 2], v3 = values[t * 4 + 3];
    float m = fmaxf(fmaxf(v0, v1), fmaxf(v2, v3));
    float e0 = expf(v0 - m), e1 = expf(v1 - m), e2 = expf(v2 - m), e3 = expf(v3 - m);
    float inv = 4.0f / (e0 + e1 + e2 + e3);
    float xk = e0 * inv, yk = e1 * inv, zk = e2 * inv, wk = e3 * inv;
    kv[t * 4 + 0] = (xk + yk - 2.0f) * 0.25f;
    kv[t * 4 + 1] = (xk + zk - 2.0f) * 0.25f;
    kv[t * 4 + 2] = (xk + wk - 2.0f) * 0.125f;
    kv[t * 4 + 3] = 0.f;
  }
}

// ---------------------------------------------------------------------------
// K1: A_bar, B_coeff in double
// ---------------------------------------------------------------------------
__global__ void k_coeff(const float* __restrict__ Lre, const float* __restrict__ Lim,
                        const float* __restrict__ log_step, const float* __restrict__ kv,
                        float2* __restrict__ A, float2* __restrict__ Bc) {
  int tid = blockIdx.x * blockDim.x + threadIdx.x;
  int n = tid >> 6, p = tid & 63;
  int h = n >> 5, w = n & 31;
  double ch = 2.0 * cos(M_PI * (double)(h + 1) / 33.0);
  double cw = 2.0 * cos(M_PI * (double)(w + 1) / 33.0);
  double Dv = (double)kv[p * 4 + 0] * cw + (double)kv[p * 4 + 1] * ch +
              (double)kv[p * 4 + 2] * ch * cw + 1.0;
  double lr = fmin((double)Lre[p], -0.0001);
  double li = (double)Lim[p];
  double tr = lr * Dv, ti = li * Dv;
  double st = exp((double)log_step[p]);
  double zr = tr * st, zi = ti * st;
  double ea = exp(zr);
  double Ar = ea * cos(zi), Ai = ea * sin(zi);
  double d = tr * tr + ti * ti;
  double br = ((Ar - 1.0) * tr + Ai * ti) / d;
  double bi = (Ai * tr - (Ar - 1.0) * ti) / d;
  A[tid]  = make_float2((float)Ar, (float)Ai);
  Bc[tid] = make_float2((float)br, (float)bi);
}

// ---------------------------------------------------------------------------
// K1b: pack conv weights into MFMA-fragment order, split bf16 hi/lo.
// ---------------------------------------------------------------------------
#define NB_PACK (18 * 8 * 64 * 8)    // 73728
#define NC_PACK (54 * 4 * 64 * 8)    // 110592
__global__ __launch_bounds__(256) void k_pack(
    const float* __restrict__ Br, const float* __restrict__ Bi,
    const float* __restrict__ Cr, const float* __restrict__ Ci,
    const float* __restrict__ Dk,
    u16* __restrict__ WBhi, u16* __restrict__ WBlo,
    u16* __restrict__ WChi, u16* __restrict__ WClo) {
  int tid = blockIdx.x * 256 + threadIdx.x;
  if (tid < NB_PACK) {
    int j = tid & 7, lane = (tid >> 3) & 63, nt = (tid >> 9) & 7, kc = tid >> 12;
    int k = kc * 32 + ((lane >> 4) << 3) + j;
    int n = nt * 16 + (lane & 15);
    int tap = k >> 6, c = k & 63;
    float w = (n < 64) ? Br[(tap * 64 + c) * 64 + n]
                       : Bi[(tap * 64 + c) * 64 + (n - 64)];
    u16 hi = f2bf(w);
    WBhi[tid] = hi;
    WBlo[tid] = f2bf(w - bf2f(hi));
  } else {
    int t2 = tid - NB_PACK;
    if (t2 < NC_PACK) {
      int j = t2 & 7, lane = (t2 >> 3) & 63, nt = (t2 >> 9) & 3, kc = t2 >> 11;
      int k = kc * 32 + ((lane >> 4) << 3) + j;     // 0..1727
      int n = nt * 16 + (lane & 15);                 // 0..63
      int s = k / 576, rem = k % 576;
      int tap = rem >> 6, c = rem & 63;
      int widx = (tap * 64 + c) * 64 + n;
      float w = (s == 0) ? 2.f * Cr[widx] : (s == 1) ? -2.f * Ci[widx] : Dk[widx];
      u16 hi = f2bf(w);
      WChi[t2] = hi;
      WClo[t2] = f2bf(w - bf2f(hi));
    }
  }
}

// ---------------------------------------------------------------------------
// K2: convB via MFMA (unchanged from round 4)
// ---------------------------------------------------------------------------
__global__ __launch_bounds__(256) void k_convB_mfma(
    const float* __restrict__ u, const float* __restrict__ x0,
    const u16* __restrict__ WBhi, const u16* __restrict__ WBlo,
    float2* __restrict__ XBUF) {
  __shared__ u16 lhs[6 * 34 * 64];
  __shared__ u16 lls[6 * 34 * 64];
  int img = blockIdx.x, h0 = blockIdx.y * 4;
  int t = threadIdx.x;
  const float* src = (img < NIMG) ? (u + (size_t)img * HWN * NU)
                                  : (x0 + (size_t)(img - NIMG) * HWN * NU);
  for (int idx = t; idx < 6 * 34 * 16; idx += 256) {
    int c4 = idx & 15, rem = idx >> 4, w = rem % 34, r = rem / 34;
    int hh = h0 - 1 + r, wg = w - 1;
    float4 v = make_float4(0.f, 0.f, 0.f, 0.f);
    if (hh >= 0 && hh < NH && wg >= 0 && wg < NW)
      v = *(const float4*)(src + (hh * 32 + wg) * 64 + c4 * 4);
    u16 a0 = f2bf(v.x), a1 = f2bf(v.y), a2 = f2bf(v.z), a3 = f2bf(v.w);
    u16 b0 = f2bf(v.x - bf2f(a0)), b1 = f2bf(v.y - bf2f(a1));
    u16 b2 = f2bf(v.z - bf2f(a2)), b3 = f2bf(v.w - bf2f(a3));
    int a = (r * 34 + w) * 64 + (((c4 >> 1) ^ (w & 7)) << 3) + ((c4 & 1) << 2);
    *(ushort4*)&lhs[a] = make_ushort4(a0, a1, a2, a3);
    *(ushort4*)&lls[a] = make_ushort4(b0, b1, b2, b3);
  }
  __syncthreads();
  int lane = t & 63, wv = t >> 6;
  int mgrp = wv >> 1, ng = wv & 1;
  int l15 = lane & 15, l4 = lane >> 4;
  f32x4 acc[4][4];
#pragma unroll
  for (int i = 0; i < 4; i++)
#pragma unroll
    for (int q = 0; q < 4; q++) acc[i][q] = (f32x4){0.f, 0.f, 0.f, 0.f};

  for (int tap = 0; tap < 9; tap++) {
    int kh = tap / 3, kw = tap - kh * 3;
#pragma unroll
    for (int cc = 0; cc < 2; cc++) {
      int kc = tap * 2 + cc;
      bf16x8 ah[4], al[4], wh[4], wl[4];
#pragma unroll
      for (int mti = 0; mti < 4; mti++) {
        int row = mgrp * 2 + (mti >> 1);
        int wt = (mti & 1) * 16 + l15 + kw;
        int off = ((row + kh) * 34 + wt) * 64 + (((cc * 4 + l4) ^ (wt & 7)) << 3);
        ah[mti] = *(const bf16x8*)&lhs[off];
        al[mti] = *(const bf16x8*)&lls[off];
      }
#pragma unroll
      for (int q = 0; q < 4; q++) {
        int nt = ng * 2 + (q & 1) + (q >> 1) * 4;
        size_t woff = ((size_t)((kc * 8 + nt) * 64 + lane)) * 8;
        wh[q] = *(const bf16x8*)&WBhi[woff];
        wl[q] = *(const bf16x8*)&WBlo[woff];
      }
#pragma unroll
      for (int mti = 0; mti < 4; mti++)
#pragma unroll
        for (int q = 0; q < 4; q++) {
          f32x4 c = acc[mti][q];
          c = __builtin_amdgcn_mfma_f32_16x16x32_bf16(ah[mti], wh[q], c, 0, 0, 0);
          c = __builtin_amdgcn_mfma_f32_16x16x32_bf16(ah[mti], wl[q], c, 0, 0, 0);
          c = __builtin_amdgcn_mfma_f32_16x16x32_bf16(al[mti], wh[q], c, 0, 0, 0);
          acc[mti][q] = c;
        }
    }
  }
  float2* dst = XBUF + (size_t)img * IMG_STRIDE;
#pragma unroll
  for (int mti = 0; mti < 4; mti++) {
    int h = h0 + mgrp * 2 + (mti >> 1);
#pragma unroll
    for (int half = 0; half < 2; half++) {
      int p = ng * 32 + half * 16 + l15;
#pragma unroll
      for (int reg = 0; reg < 4; reg++) {
        int wpix = (mti & 1) * 16 + l4 * 4 + reg;
        float re = acc[mti][half][reg];
        float im = acc[mti][2 + half][reg];
        int m = (h + wpix + 2) & 3;
        float2 o;
        if (m == 0)      o = make_float2( re,  im);
        else if (m == 1) o = make_float2( im, -re);
        else if (m == 2) o = make_float2(-re, -im);
        else             o = make_float2(-im,  re);
        dst[(h * 32 + wpix) * 64 + p] = o;
      }
    }
  }
}

// ---------------------------------------------------------------------------
// K3: forward DST IN-PLACE, register-tiled. Block = (img, p-pair pc 0..31).
//     LDS 32 KB. No B_coeff here (moved to scan).
//     Stage1: t1[a][w] = sum_h S[a][h]*Y[h][w]; Stage2: Z[a][c] = sum_w t1[a][w]*S[c][w]
// ---------------------------------------------------------------------------
__global__ __launch_bounds__(256) void k_dst_fwd(float2* __restrict__ XBUF,
                                                 const float* __restrict__ S) {
  int img = blockIdx.x, pc = blockIdx.y;
  __shared__ float tin[32 * 32 * 4];   // [d1][d2][pp*2+ri]
  __shared__ float t1 [32 * 32 * 4];   // [o1][d2 ^ (ag&7)][ppri]
  int t = threadIdx.x;
  float2* base = XBUF + (size_t)img * IMG_STRIDE;
  for (int n = t; n < 1024; n += 256) {
    float4 v = *(const float4*)&base[n * 64 + pc * 2];
    *(float4*)&tin[n * 4] = v;
  }
  __syncthreads();
  {  // stage 1
    int w = t & 31, ag = t >> 5;
    f32x4 acc[4];
#pragma unroll
    for (int i = 0; i < 4; i++) acc[i] = (f32x4){0.f, 0.f, 0.f, 0.f};
#pragma unroll 8
    for (int hh = 0; hh < 32; hh++) {
      f32x4 v = *(const f32x4*)&tin[(hh * 32 + w) * 4];
      f32x4 s4 = *(const f32x4*)&S[hh * 32 + ag * 4];
#pragma unroll
      for (int i = 0; i < 4; i++) acc[i] += s4[i] * v;
    }
    int wp = w ^ (ag & 7);
#pragma unroll
    for (int i = 0; i < 4; i++)
      *(f32x4*)&t1[((ag * 4 + i) * 32 + wp) * 4] = acc[i];
  }
  __syncthreads();
  {  // stage 2
    int pp = t & 1, cg = (t >> 1) & 15, ag = t >> 5;
    float acc[4][2][2];
#pragma unroll
    for (int i = 0; i < 4; i++)
#pragma unroll
      for (int j = 0; j < 2; j++) acc[i][j][0] = acc[i][j][1] = 0.f;
#pragma unroll 8
    for (int w = 0; w < 32; w++) {
      int wp = w ^ (ag & 7);
      float2 sc = *(const float2*)&S[w * 32 + cg * 2];
#pragma unroll
      for (int i = 0; i < 4; i++) {
        float2 tv = *(const float2*)&t1[((ag * 4 + i) * 32 + wp) * 4 + pp * 2];
        acc[i][0][0] = fmaf(tv.x, sc.x, acc[i][0][0]);
        acc[i][0][1] = fmaf(tv.y, sc.x, acc[i][0][1]);
        acc[i][1][0] = fmaf(tv.x, sc.y, acc[i][1][0]);
        acc[i][1][1] = fmaf(tv.y, sc.y, acc[i][1][1]);
      }
    }
#pragma unroll
    for (int i = 0; i < 4; i++)
#pragma unroll
      for (int j = 0; j < 2; j++) {
        int n = (ag * 4 + i) * 32 + cg * 2 + j;
        base[n * 64 + pc * 2 + pp] = make_float2(acc[i][j][0], acc[i][j][1]);
      }
  }
}

// ---------------------------------------------------------------------------
// K4: scan over l, now applying B_coeff here: x_l = A*x_{l-1} + Bc*v_l,
//     x_{-1} = Bc*v_x0.
// ---------------------------------------------------------------------------
__global__ __launch_bounds__(256) void k_scan(const float2* __restrict__ A,
                                              const float2* __restrict__ Bc,
                                              float2* __restrict__ X) {
  int gx = blockIdx.x;
  int b = gx >> 8, a = (gx >> 3) & 31, cg = gx & 7;
  int t = threadIdx.x;
  int c = cg * 4 + (t >> 6), p = t & 63;
  size_t off = (size_t)(a * 32 + c) * 64 + p;
  float2 Av = A[off];
  float2 Bv = Bc[off];
  float2 v0 = X[(size_t)(NIMG + b) * IMG_STRIDE + off];
  float2 x;
  x.x = Bv.x * v0.x - Bv.y * v0.y;
  x.y = Bv.x * v0.y + Bv.y * v0.x;
  for (int l = 0; l < NL; l++) {
    size_t idx = (size_t)(l * NB + b) * IMG_STRIDE + off;
    float2 v = X[idx];
    float vr = Bv.x * v.x - Bv.y * v.y;
    float vi = Bv.x * v.y + Bv.y * v.x;
    float2 nx;
    nx.x = Av.x * x.x - Av.y * x.y + vr;
    nx.y = Av.x * x.y + Av.y * x.x + vi;
    x = nx;
    X[idx] = x;
  }
}

// ---------------------------------------------------------------------------
// K5: inverse DST IN-PLACE, register-tiled, + phase + bf16-split pack.
//     Per pixel 512B slot: [pc-pair 32][comp 2][pp 2][hi,lo u16] — each block
//     (img, pc) writes exactly the 16B/pixel window it read (race-free).
// ---------------------------------------------------------------------------
__global__ __launch_bounds__(256) void k_dst_inv(float2* __restrict__ XBUF,
                                                 const float* __restrict__ S) {
  int img = blockIdx.x, pc = blockIdx.y;
  __shared__ float tin[32 * 32 * 4];   // [a][c][ppri]
  __shared__ float t1 [32 * 32 * 4];   // [h][c ^ (ag&7)][ppri]
  int t = threadIdx.x;
  float2* base = XBUF + (size_t)img * IMG_STRIDE;
  for (int n = t; n < 1024; n += 256) {
    float4 v = *(const float4*)&base[n * 64 + pc * 2];
    *(float4*)&tin[n * 4] = v;
  }
  __syncthreads();
  {  // stage 1: t1[h][c] = sum_a S[h][a] * xin[a][c]
    int c = t & 31, ag = t >> 5;
    f32x4 acc[4];
#pragma unroll
    for (int i = 0; i < 4; i++) acc[i] = (f32x4){0.f, 0.f, 0.f, 0.f};
#pragma unroll 8
    for (int a = 0; a < 32; a++) {
      f32x4 v = *(const f32x4*)&tin[(a * 32 + c) * 4];
      f32x4 s4 = *(const f32x4*)&S[a * 32 + ag * 4];
#pragma unroll
      for (int i = 0; i < 4; i++) acc[i] += s4[i] * v;
    }
    int cp = c ^ (ag & 7);
#pragma unroll
    for (int i = 0; i < 4; i++)
      *(f32x4*)&t1[((ag * 4 + i) * 32 + cp) * 4] = acc[i];
  }
  __syncthreads();
  {  // stage 2: out[h][w] = sum_c S[w][c] * t1[h][c]; phase; split-pack
    int pp = t & 1, wg = (t >> 1) & 15, ag = t >> 5;
    float acc[4][2][2];
#pragma unroll
    for (int i = 0; i < 4; i++)
#pragma unroll
      for (int j = 0; j < 2; j++) acc[i][j][0] = acc[i][j][1] = 0.f;
#pragma unroll 8
    for (int c = 0; c < 32; c++) {
      int cp = c ^ (ag & 7);
      float2 sc = *(const float2*)&S[c * 32 + wg * 2];
#pragma unroll
      for (int i = 0; i < 4; i++) {
        float2 tv = *(const float2*)&t1[((ag * 4 + i) * 32 + cp) * 4 + pp * 2];
        acc[i][0][0] = fmaf(tv.x, sc.x, acc[i][0][0]);
        acc[i][0][1] = fmaf(tv.y, sc.x, acc[i][0][1]);
        acc[i][1][0] = fmaf(tv.x, sc.y, acc[i][1][0]);
        acc[i][1][1] = fmaf(tv.y, sc.y, acc[i][1][1]);
      }
    }
    u32* gw = (u32*)base;
#pragma unroll
    for (int i = 0; i < 4; i++)
#pragma unroll
      for (int j = 0; j < 2; j++) {
        int h = ag * 4 + i, wpx = wg * 2 + j;
        float re = acc[i][j][0], im = acc[i][j][1];
        int m = (h + wpx + 2) & 3;
        float2 o;
        if (m == 0)      o = make_float2( re,  im);
        else if (m == 1) o = make_float2(-im,  re);
        else if (m == 2) o = make_float2(-re, -im);
        else             o = make_float2( im, -re);
        u16 hr = f2bf(o.x), lr = f2bf(o.x - bf2f(hr));
        u16 hm = f2bf(o.y), lm = f2bf(o.y - bf2f(hm));
        int pix = h * 32 + wpx;
        gw[pix * 128 + pc * 4 + 0 + pp * 0 + pp] = 0;  // placeholder removed below
        gw[pix * 128 + pc * 4 + pp]     = (u32)hr | ((u32)lr << 16);   // comp 0 (re)
        gw[pix * 128 + pc * 4 + 2 + pp] = (u32)hm | ((u32)lm << 16);   // comp 1 (im)
      }
  }
}

// ---------------------------------------------------------------------------
// K6: convCD via MFMA + gelu; xr/xi unpack adjusted to the new slot layout.
// ---------------------------------------------------------------------------
__global__ __launch_bounds__(256) void k_convCD_mfma(
    const u32* __restrict__ XP,      // XBUF viewed as packed slots
    const float* __restrict__ u,
    const u16* __restrict__ WChi, const u16* __restrict__ WClo,
    float* __restrict__ out) {
  __shared__ u16 lhs[6 * 34 * 64];
  __shared__ u16 lls[6 * 34 * 64];
  int img = blockIdx.x, h0 = blockIdx.y * 4;
  int t = threadIdx.x;
  int lane = t & 63, wv = t >> 6;
  int mgrp = wv >> 1, ng = wv & 1;
  int l15 = lane & 15, l4 = lane >> 4;
  const u32* xim = XP + (size_t)img * IMG_STRIDE * 2;   // 131072 u32 per image
  const float* uim = u + (size_t)img * HWN * NU;
  f32x4 acc[4][2];
#pragma unroll
  for (int i = 0; i < 4; i++) {
    acc[i][0] = (f32x4){0.f, 0.f, 0.f, 0.f};
    acc[i][1] = (f32x4){0.f, 0.f, 0.f, 0.f};
  }

  for (int s = 0; s < 3; s++) {
    __syncthreads();
    if (s < 2) {
      // comp s (re/im), 4-p chunk pc4: two uint2 at [pix*128 + pc4*8 + s*2 (+4)]
      for (int idx = t; idx < 6 * 34 * 16; idx += 256) {
        int pc4 = idx & 15, rem = idx >> 4, w = rem % 34, r = rem / 34;
        int hh = h0 - 1 + r, wg = w - 1;
        uint2 d0 = make_uint2(0u, 0u), d1 = make_uint2(0u, 0u);
        if (hh >= 0 && hh < NH && wg >= 0 && wg < NW) {
          const u32* gp = xim + (hh * 32 + wg) * 128 + pc4 * 8 + s * 2;
          d0 = *(const uint2*)gp;
          d1 = *(const uint2*)(gp + 4);
        }
        int a = (r * 34 + w) * 64 + (((pc4 >> 1) ^ (w & 7)) << 3) + ((pc4 & 1) << 2);
        *(ushort4*)&lhs[a] = make_ushort4((u16)(d0.x & 0xffff), (u16)(d0.y & 0xffff),
                                          (u16)(d1.x & 0xffff), (u16)(d1.y & 0xffff));
        *(ushort4*)&lls[a] = make_ushort4((u16)(d0.x >> 16), (u16)(d0.y >> 16),
                                          (u16)(d1.x >> 16), (u16)(d1.y >> 16));
      }
    } else {
      for (int idx = t; idx < 6 * 34 * 16; idx += 256) {
        int c4 = idx & 15, rem = idx >> 4, w = rem % 34, r = rem / 34;
        int hh = h0 - 1 + r, wg = w - 1;
        float4 v = make_float4(0.f, 0.f, 0.f, 0.f);
        if (hh >= 0 && hh < NH && wg >= 0 && wg < NW)
          v = *(const float4*)(uim + (hh * 32 + wg) * 64 + c4 * 4);
        u16 a0 = f2bf(v.x), a1 = f2bf(v.y), a2 = f2bf(v.z), a3 = f2bf(v.w);
        u16 b0 = f2bf(v.x - bf2f(a0)), b1 = f2bf(v.y - bf2f(a1));
        u16 b2 = f2bf(v.z - bf2f(a2)), b3 = f2bf(v.w - bf2f(a3));
        int a = (r * 34 + w) * 64 + (((c4 >> 1) ^ (w & 7)) << 3) + ((c4 & 1) << 2);
        *(ushort4*)&lhs[a] = make_ushort4(a0, a1, a2, a3);
        *(ushort4*)&lls[a] = make_ushort4(b0, b1, b2, b3);
      }
    }
    __syncthreads();
    for (int tap = 0; tap < 9; tap++) {
      int kh = tap / 3, kw = tap - kh * 3;
#pragma unroll
      for (int cc = 0; cc < 2; cc++) {
        int kc = (s * 9 + tap) * 2 + cc;
        bf16x8 ah[4], al[4], wh[2], wl[2];
#pragma unroll
        for (int mti = 0; mti < 4; mti++) {
          int row = mgrp * 2 + (mti >> 1);
          int wt = (mti & 1) * 16 + l15 + kw;
          int off = ((row + kh) * 34 + wt) * 64 + (((cc * 4 + l4) ^ (wt & 7)) << 3);
          ah[mti] = *(const bf16x8*)&lhs[off];
          al[mti] = *(const bf16x8*)&lls[off];
        }
#pragma unroll
        for (int q = 0; q < 2; q++) {
          int nt = ng * 2 + q;
          size_t woff = ((size_t)((kc * 4 + nt) * 64 + lane)) * 8;
          wh[q] = *(const bf16x8*)&WChi[woff];
          wl[q] = *(const bf16x8*)&WClo[woff];
        }
#pragma unroll
        for (int mti = 0; mti < 4; mti++)
#pragma unroll
          for (int q = 0; q < 2; q++) {
            f32x4 c = acc[mti][q];
            c = __builtin_amdgcn_mfma_f32_16x16x32_bf16(ah[mti], wh[q], c, 0, 0, 0);
            c = __builtin_amdgcn_mfma_f32_16x16x32_bf16(ah[mti], wl[q], c, 0, 0, 0);
            c = __builtin_amdgcn_mfma_f32_16x16x32_bf16(al[mti], wh[q], c, 0, 0, 0);
            acc[mti][q] = c;
          }
      }
    }
  }
  float* dst = out + (size_t)img * HWN * NU;
#pragma unroll
  for (int mti = 0; mti < 4; mti++) {
    int h = h0 + mgrp * 2 + (mti >> 1);
#pragma unroll
    for (int q = 0; q < 2; q++) {
      int un = (ng * 2 + q) * 16 + l15;
#pragma unroll
      for (int reg = 0; reg < 4; reg++) {
        int wpix = (mti & 1) * 16 + l4 * 4 + reg;
        float x = acc[mti][q][reg];
        float z = 0.7978845608028654f * (x + 0.044715f * x * x * x);
        float e = __expf(2.f * z);
        float th = 1.f - 2.f / (e + 1.f);
        dst[(h * 32 + wpix) * 64 + un] = 0.5f * x * (1.f + th);
      }
    }
  }
}

// ---------------------------------------------------------------------------
extern "C" void kernel_launch(void* const* d_in, const int* in_sizes, int n_in,
                              void* d_out, int out_size, void* d_ws, size_t ws_size,
                              hipStream_t stream) {
  const float* u        = (const float*)d_in[0];
  const float* x0       = (const float*)d_in[1];
  const float* Lre      = (const float*)d_in[2];
  const float* Lim      = (const float*)d_in[3];
  const float* values   = (const float*)d_in[4];
  const float* log_step = (const float*)d_in[5];
  const float* Br       = (const float*)d_in[6];
  const float* Bi       = (const float*)d_in[7];
  const float* Cr       = (const float*)d_in[8];
  const float* Ci       = (const float*)d_in[9];
  const float* Dk       = (const float*)d_in[10];
  float* out = (float*)d_out;

  char* ws = (char*)d_ws;
  float*  S    = (float*)ws;                       ws += 4096;
  float*  kv   = (float*)ws;                       ws += 4096;
  float2* A    = (float2*)ws;                      ws += 524288;
  float2* Bc   = (float2*)ws;                      ws += 524288;
  u16*    WBhi = (u16*)ws;                         ws += NB_PACK * 2;
  u16*    WBlo = (u16*)ws;                         ws += NB_PACK * 2;
  u16*    WChi = (u16*)ws;                         ws += NC_PACK * 2;
  u16*    WClo = (u16*)ws;                         ws += NC_PACK * 2;
  float2* XBUF = (float2*)ws;

  hipLaunchKernelGGL(k_setup,      dim3(1),            dim3(1024), 0, stream, values, S, kv);
  hipLaunchKernelGGL(k_coeff,      dim3(256),          dim3(256),  0, stream, Lre, Lim, log_step, kv, A, Bc);
  hipLaunchKernelGGL(k_pack,       dim3(720),          dim3(256),  0, stream, Br, Bi, Cr, Ci, Dk, WBhi, WBlo, WChi, WClo);
  hipLaunchKernelGGL(k_convB_mfma, dim3(NIMG_TOT, 8),  dim3(256),  0, stream, u, x0, WBhi, WBlo, XBUF);
  hipLaunchKernelGGL(k_dst_fwd,    dim3(NIMG_TOT, 32), dim3(256),  0, stream, XBUF, S);
  hipLaunchKernelGGL(k_scan,       dim3(2048),         dim3(256),  0, stream, A, Bc, XBUF);
  hipLaunchKernelGGL(k_dst_inv,    dim3(NIMG, 32),     dim3(256),  0, stream, XBUF, S);
  hipLaunchKernelGGL(k_convCD_mfma,dim3(NIMG, 8),      dim3(256),  0, stream, (const u32*)XBUF, u, WChi, WClo, out);
}